// Round 10
// baseline (242.256 us; speedup 1.0000x reference)
//
#include <hip/hip_runtime.h>

#define NN 4096
#define NE 8192
#define NLG 32768
#define CAP 32
#define CAP2 160   // 2-hop expansion bucket

typedef unsigned int u32;
typedef unsigned short u16;
typedef __attribute__((ext_vector_type(4))) float f32x4;
typedef __attribute__((ext_vector_type(8))) short bf16x8;
typedef __attribute__((ext_vector_type(8))) unsigned short u16x8;
typedef __attribute__((ext_vector_type(4))) unsigned short u16x4;

__device__ __forceinline__ float bf2f(u16 u) { return __uint_as_float(((u32)u) << 16); }
__device__ __forceinline__ u16 f2bf(float f) {
    u32 x = __float_as_uint(f);
    return (u16)((x + 0x7fffu + ((x >> 16) & 1u)) >> 16);  // RNE
}

// ================= K1: prep (converts/transposes/bias) + bucket append, fused =================
struct PAArgs {
    const float *x, *ex;
    const float *nW0, *nW1, *eWl0, *eWu0, *eWl1, *eWu1, *fnW, *feW, *nb0, *nb1;
    const int *nei, *eil, *eiu;
    u32 *cntA, *cntL, *cntU;            // raw counters (zeroed by memset)
    u32 *colA, *colL, *colU, *eidL, *eidU;
    u16 *Zb1n, *Zb1e, *nW0T, *nW1T, *eW1T, *eW2T, *fnWT, *feWT;
    float *nb0s, *nb1s;
};

__device__ __forceinline__ void wtrK(const float* src, u16* dst, u32 i, int Kp, int Nw, int ld, int kofs) {
    int nn = i / Kp, kk = i - nn * Kp;
    dst[(size_t)nn * ld + kofs + kk] = f2bf(src[(size_t)kk * Nw + nn]);
}
__device__ __forceinline__ void wtrS(const float* sa, const float* sb, u16* dst, u32 i, int Kp, int Nw, int ld) {
    int nn = i / Kp, kk = i - nn * Kp;
    dst[(size_t)nn * ld + kk] = f2bf(sa[(size_t)kk * Nw + nn] + sb[(size_t)kk * Nw + nn]);
}

__global__ __launch_bounds__(256) void prep_append(PAArgs A) {
    const u32 gid = blockIdx.x * blockDim.x + threadIdx.x;
    const u32 gsz = gridDim.x * blockDim.x;
    const u32 C0 = 65536;                 // x conv (f32x4 units)
    const u32 C1 = C0 + 65536;            // ex conv
    const u32 C2 = C1 + 24576;            // nW0T (Kp=192)
    const u32 C3 = C2 + 49152;            // nW1T (Kp=384)
    const u32 C4 = C3 + 4096;             // eW1T sum block (Kp=32)
    const u32 C5 = C4 + 4096;             // eWl0 k=1
    const u32 C6 = C5 + 4096;             // eWl0 k=2
    const u32 C7 = C6 + 4096;             // eWu0 k=1
    const u32 C8 = C7 + 4096;             // eWu0 k=2
    const u32 C9 = C8 + 16384;            // eW2T sum block (Kp=128)
    const u32 C10 = C9 + 16384;           // eWl1 k=1
    const u32 C11 = C10 + 16384;          // eWl1 k=2
    const u32 C12 = C11 + 16384;          // eWu1 k=1
    const u32 C13 = C12 + 16384;          // eWu1 k=2
    const u32 C14 = C13 + 8192;           // fnWT
    const u32 C15 = C14 + 8192;           // feWT
    const u32 C16 = C15 + 256;            // bias sums
    const u32 C17 = C16 + (NE + 2 * NLG); // append
    for (u32 i = gid; i < C17; i += gsz) {
        if (i < C0) {
            u32 t = i; int r = t >> 4, c4 = t & 15;
            f32x4 v = *(const f32x4*)(A.x + (size_t)t * 4);
            u16x4 o;
#pragma unroll
            for (int e = 0; e < 4; ++e) o[e] = f2bf(v[e]);
            *(u16x4*)(A.Zb1n + (size_t)r * 192 + c4 * 4) = o;
        } else if (i < C1) {
            u32 t = i - C0; int r = t >> 3, c4 = t & 7;
            f32x4 v = *(const f32x4*)(A.ex + (size_t)t * 4);
            u16x4 o;
#pragma unroll
            for (int e = 0; e < 4; ++e) o[e] = f2bf(v[e]);
            *(u16x4*)(A.Zb1e + (size_t)r * 160 + c4 * 4) = o;
        }
        else if (i < C2)  wtrK(A.nW0, A.nW0T, i - C1, 192, 128, 192, 0);
        else if (i < C3)  wtrK(A.nW1, A.nW1T, i - C2, 384, 128, 384, 0);
        else if (i < C4)  wtrS(A.eWl0, A.eWu0, A.eW1T, i - C3, 32, 128, 160);
        else if (i < C5)  wtrK(A.eWl0 + 32 * 128,     A.eW1T, i - C4, 32, 128, 160, 32);
        else if (i < C6)  wtrK(A.eWl0 + 2 * 32 * 128, A.eW1T, i - C5, 32, 128, 160, 64);
        else if (i < C7)  wtrK(A.eWu0 + 32 * 128,     A.eW1T, i - C6, 32, 128, 160, 96);
        else if (i < C8)  wtrK(A.eWu0 + 2 * 32 * 128, A.eW1T, i - C7, 32, 128, 160, 128);
        else if (i < C9)  wtrS(A.eWl1, A.eWu1, A.eW2T, i - C8, 128, 128, 640);
        else if (i < C10) wtrK(A.eWl1 + 128 * 128,     A.eW2T, i - C9, 128, 128, 640, 128);
        else if (i < C11) wtrK(A.eWl1 + 2 * 128 * 128, A.eW2T, i - C10, 128, 128, 640, 256);
        else if (i < C12) wtrK(A.eWu1 + 128 * 128,     A.eW2T, i - C11, 128, 128, 640, 384);
        else if (i < C13) wtrK(A.eWu1 + 2 * 128 * 128, A.eW2T, i - C12, 128, 128, 640, 512);
        else if (i < C14) wtrK(A.fnW, A.fnWT, i - C13, 128, 64, 128, 0);
        else if (i < C15) wtrK(A.feW, A.feWT, i - C14, 128, 64, 128, 0);
        else if (i < C16) {
            u32 t = i - C15;
            if (t < 128) { float s = 0.f; for (int k = 0; k < 3; ++k) s += A.nb0[k * 128 + t]; A.nb0s[t] = s; }
            else { t -= 128; float s = 0.f; for (int k = 0; k < 3; ++k) s += A.nb1[k * 128 + t]; A.nb1s[t] = s; }
        } else {
            u32 t = i - C16;
            if (t < NE) {
                int r = A.nei[t];
                u32 p = atomicAdd(&A.cntA[r], 1u);
                if (p < CAP) A.colA[r * CAP + p] = (u32)A.nei[NE + t];
            } else if (t < NE + NLG) {
                u32 e = t - NE;
                int r = A.eil[e];
                u32 p = atomicAdd(&A.cntL[r], 1u);
                if (p < CAP) { A.colL[r * CAP + p] = (u32)A.eil[NLG + e]; A.eidL[r * CAP + p] = e; }
            } else {
                u32 e = t - NE - NLG;
                int r = A.eiu[e];
                u32 p = atomicAdd(&A.cntU[r], 1u);
                if (p < CAP) { A.colU[r * CAP + p] = (u32)A.eiu[NLG + e]; A.eidU[r * CAP + p] = e; }
            }
        }
    }
}

// ================= K2: merged parallel resolve + square — one thread per (row, slot) =================
// Dedup semantics: A first-index-wins (binary, value-identical); L/U max-eid-wins (jnp last-set-wins).
// Square reads RAW neighbor buckets (re-dedup inline) -> no cross-thread rb1 dependency.
struct RQArgs {
    const u32 *cntA, *cntL, *cntU;
    const u32 *colA, *colL, *colU, *eidL, *eidU;
    const float *eal, *eau;
    u32 *cnt1A, *cnt1L, *cnt1U;       // zeroed
    u32 *cnt2A, *cnt2L, *cnt2U;       // zeroed
    uint2 *rb1A, *rb1L, *rb1U;
    uint2 *rb2A, *rb2L, *rb2U;
};

__global__ __launch_bounds__(256) void resolve_square_par(RQArgs A) {
    u32 id = blockIdx.x * blockDim.x + threadIdx.x;
    const u32 NA = NN * CAP, NL = NE * CAP;
    if (id < NA) {
        u32 row = id >> 5, j = id & 31;
        u32 jn = A.cntA[row]; if (jn > CAP) jn = CAP;
        if (j >= jn) return;
        const u32* cp = A.colA + row * CAP;
        u32 cj = cp[j];
        for (u32 j2 = 0; j2 < j; ++j2) if (cp[j2] == cj) return;  // not first occurrence
        u32 pos = atomicAdd(&A.cnt1A[row], 1u);
        A.rb1A[row * CAP + pos] = make_uint2(cj, __float_as_uint(1.0f));
        // expand neighbor row cj from RAW bucket (first-occurrence dedup)
        u32 kn = A.cntA[cj]; if (kn > CAP) kn = CAP;
        const u32* cq = A.colA + cj * CAP;
        u32 m = 0;
        for (u32 k = 0; k < kn; ++k) {
            u32 ck = cq[k];
            bool f = true;
            for (u32 k2 = 0; k2 < k; ++k2) if (cq[k2] == ck) f = false;
            if (f) ++m;
        }
        u32 off = atomicAdd(&A.cnt2A[row], m);
        uint2* op = A.rb2A + (size_t)row * CAP2;
        u32 p = off;
        for (u32 k = 0; k < kn; ++k) {
            u32 ck = cq[k];
            bool f = true;
            for (u32 k2 = 0; k2 < k; ++k2) if (cq[k2] == ck) f = false;
            if (f) { if (p < CAP2) op[p] = make_uint2(ck, __float_as_uint(1.0f)); ++p; }
        }
    } else if (id < NA + 2 * NL) {
        bool isL = id < NA + NL;
        u32 t = isL ? (id - NA) : (id - NA - NL);
        u32 row = t >> 5, j = t & 31;
        const u32* cnt = isL ? A.cntL : A.cntU;
        u32 jn = cnt[row]; if (jn > CAP) jn = CAP;
        if (j >= jn) return;
        const u32* cp = (isL ? A.colL : A.colU) + row * CAP;
        const u32* ep = (isL ? A.eidL : A.eidU) + row * CAP;
        u32 cj = cp[j], ej = ep[j];
        for (u32 j2 = 0; j2 < jn; ++j2)
            if (j2 != j && cp[j2] == cj && ep[j2] > ej) return;  // not last-set winner
        const float* attr = isL ? A.eal : A.eau;
        float w1 = attr[ej];
        u32* c1 = isL ? A.cnt1L : A.cnt1U;
        uint2* rb1 = isL ? A.rb1L : A.rb1U;
        u32 pos = atomicAdd(&c1[row], 1u);
        rb1[row * CAP + pos] = make_uint2(cj, __float_as_uint(w1));
        // expand neighbor row cj from RAW bucket (max-eid dedup)
        u32 kn = cnt[cj]; if (kn > CAP) kn = CAP;
        const u32* cq = (isL ? A.colL : A.colU) + cj * CAP;
        const u32* eq = (isL ? A.eidL : A.eidU) + cj * CAP;
        u32 m = 0;
        for (u32 k = 0; k < kn; ++k) {
            u32 ck = cq[k], ek = eq[k];
            bool w = true;
            for (u32 k2 = 0; k2 < kn; ++k2)
                if (k2 != k && cq[k2] == ck && eq[k2] > ek) w = false;
            if (w) ++m;
        }
        u32* c2 = isL ? A.cnt2L : A.cnt2U;
        uint2* rb2 = isL ? A.rb2L : A.rb2U;
        u32 off = atomicAdd(&c2[row], m);
        uint2* op = rb2 + (size_t)row * CAP2;
        u32 p = off;
        for (u32 k = 0; k < kn; ++k) {
            u32 ck = cq[k], ek = eq[k];
            bool w = true;
            for (u32 k2 = 0; k2 < kn; ++k2)
                if (k2 != k && cq[k2] == ck && eq[k2] > ek) w = false;
            if (w) { if (p < CAP2) op[p] = make_uint2(ck, __float_as_uint(w1 * attr[ek])); ++p; }
        }
    }
}

// ================= one-hop gather SpMM over resolved buckets (exact counts), 6 segments =================
struct RSeg { const u32* cnt; const uint2* rb; u32 rbs; const u16* src; u16* dst; int n; int shift; int ld; };
struct Seg6 { RSeg s[6]; };

__device__ __forceinline__ void spmm_row8(const RSeg& s, int t) {
    int row = t >> s.shift, g = t & ((1 << s.shift) - 1);
    u32 jn = s.cnt[row]; if (jn > s.rbs) jn = s.rbs;
    const uint2* bp = s.rb + (size_t)row * s.rbs;
    const u16* srcg = s.src + g * 8;
    float acc[8] = {};
    u32 j = 0;
    for (; j + 4 <= jn; j += 4) {
        uint2 q0 = bp[j], q1 = bp[j + 1], q2 = bp[j + 2], q3 = bp[j + 3];
        u16x8 x0 = *(const u16x8*)(srcg + (size_t)q0.x * s.ld);
        u16x8 x1 = *(const u16x8*)(srcg + (size_t)q1.x * s.ld);
        u16x8 x2 = *(const u16x8*)(srcg + (size_t)q2.x * s.ld);
        u16x8 x3 = *(const u16x8*)(srcg + (size_t)q3.x * s.ld);
        float w0 = __uint_as_float(q0.y), w1 = __uint_as_float(q1.y);
        float w2 = __uint_as_float(q2.y), w3 = __uint_as_float(q3.y);
#pragma unroll
        for (int e = 0; e < 8; ++e) {
            acc[e] = fmaf(w0, bf2f(x0[e]), acc[e]);
            acc[e] = fmaf(w1, bf2f(x1[e]), acc[e]);
            acc[e] = fmaf(w2, bf2f(x2[e]), acc[e]);
            acc[e] = fmaf(w3, bf2f(x3[e]), acc[e]);
        }
    }
    for (; j < jn; ++j) {
        uint2 q = bp[j];
        u16x8 xv = *(const u16x8*)(srcg + (size_t)q.x * s.ld);
        float w = __uint_as_float(q.y);
#pragma unroll
        for (int e = 0; e < 8; ++e) acc[e] = fmaf(w, bf2f(xv[e]), acc[e]);
    }
    u16x8 o;
#pragma unroll
    for (int e = 0; e < 8; ++e) o[e] = f2bf(acc[e]);
    *(u16x8*)(s.dst + (size_t)row * s.ld + g * 8) = o;
}

__device__ __forceinline__ void spmm_row4(const RSeg& s, int t) {
    int row = t >> s.shift, g = t & ((1 << s.shift) - 1);
    u32 jn = s.cnt[row]; if (jn > s.rbs) jn = s.rbs;
    const uint2* bp = s.rb + (size_t)row * s.rbs;
    const u16* srcg = s.src + g * 4;
    float acc[4] = {};
    u32 j = 0;
    for (; j + 4 <= jn; j += 4) {
        uint2 q0 = bp[j], q1 = bp[j + 1], q2 = bp[j + 2], q3 = bp[j + 3];
        u16x4 x0 = *(const u16x4*)(srcg + (size_t)q0.x * s.ld);
        u16x4 x1 = *(const u16x4*)(srcg + (size_t)q1.x * s.ld);
        u16x4 x2 = *(const u16x4*)(srcg + (size_t)q2.x * s.ld);
        u16x4 x3 = *(const u16x4*)(srcg + (size_t)q3.x * s.ld);
        float w0 = __uint_as_float(q0.y), w1 = __uint_as_float(q1.y);
        float w2 = __uint_as_float(q2.y), w3 = __uint_as_float(q3.y);
#pragma unroll
        for (int e = 0; e < 4; ++e) {
            acc[e] = fmaf(w0, bf2f(x0[e]), acc[e]);
            acc[e] = fmaf(w1, bf2f(x1[e]), acc[e]);
            acc[e] = fmaf(w2, bf2f(x2[e]), acc[e]);
            acc[e] = fmaf(w3, bf2f(x3[e]), acc[e]);
        }
    }
    for (; j < jn; ++j) {
        uint2 q = bp[j];
        u16x4 xv = *(const u16x4*)(srcg + (size_t)q.x * s.ld);
        float w = __uint_as_float(q.y);
#pragma unroll
        for (int e = 0; e < 4; ++e) acc[e] = fmaf(w, bf2f(xv[e]), acc[e]);
    }
    u16x4 o;
#pragma unroll
    for (int e = 0; e < 4; ++e) o[e] = f2bf(acc[e]);
    *(u16x4*)(s.dst + (size_t)row * s.ld + g * 4) = o;
}

__global__ __launch_bounds__(256) void spmm4_kernel(Seg6 P) {
    int id = blockIdx.x * blockDim.x + threadIdx.x;
    int base = 0;
#pragma unroll
    for (int i = 0; i < 6; ++i) {
        int n = P.s[i].n;
        if (id < base + n) { spmm_row4(P.s[i], id - base); return; }
        base += n;
    }
}

__global__ __launch_bounds__(256) void spmm8_kernel(Seg6 P) {
    int id = blockIdx.x * blockDim.x + threadIdx.x;
    int base = 0;
#pragma unroll
    for (int i = 0; i < 6; ++i) {
        int n = P.s[i].n;
        if (id < base + n) { spmm_row8(P.s[i], id - base); return; }
        base += n;
    }
}

// ================= MFMA GEMM =================
struct G { const u16* Aa; int lda; const u16* WT; int K; const float* bias;
           u16* dst; int ldd; };

__device__ __forceinline__ void gemm_do(const G& g, int bx, int ny, int lane) {
    int m0 = bx * 16, n0 = ny * 64;
    int row = lane & 15, koff = (lane >> 4) * 8;
    f32x4 acc[4] = {};
    const u16* Ap = g.Aa + (size_t)(m0 + row) * g.lda + koff;
    const u16* Wp = g.WT + (size_t)(n0 + row) * g.K + koff;
    size_t ws = (size_t)16 * g.K;
    for (int k0 = 0; k0 < g.K; k0 += 32) {
        bf16x8 af = *(const bf16x8*)(Ap + k0);
#pragma unroll
        for (int nt = 0; nt < 4; ++nt) {
            bf16x8 bf = *(const bf16x8*)(Wp + nt * ws + k0);
            acc[nt] = __builtin_amdgcn_mfma_f32_16x16x32_bf16(af, bf, acc[nt], 0, 0, 0);
        }
    }
    int orow = m0 + (lane >> 4) * 4;
#pragma unroll
    for (int nt = 0; nt < 4; ++nt) {
        int col = n0 + nt * 16 + row;
        float bv = g.bias[col];
#pragma unroll
        for (int r = 0; r < 4; ++r) {
            float v = fmaxf(acc[nt][r] + bv, 0.f);  // relu
            g.dst[(size_t)(orow + r) * g.ldd + col] = f2bf(v);
        }
    }
}

__global__ __launch_bounds__(256) void gemm1_kernel(G g0, G g1) {
    int wv = threadIdx.x >> 6, lane = threadIdx.x & 63;
    int bxg = blockIdx.x * 4 + wv;
    int ny = blockIdx.y;
    if (bxg < 256) gemm_do(g0, bxg, ny, lane);
    else gemm_do(g1, bxg - 256, ny, lane);
}

// ================= fused layer-2 GEMM + output head =================
struct GHArgs {
    const u16 *Zb2n, *Zb2e, *nW1T, *eW2T, *fnWT, *feWT;
    const float *nb1s, *eb1, *fnb, *feb;
    float *outn, *oute;
};

__global__ __launch_bounds__(256) void gemm2_head(GHArgs A) {
    __shared__ u16 lds[4][16 * 128];
    int wv = threadIdx.x >> 6, lane = threadIdx.x & 63;
    int s = blockIdx.x * 4 + wv;
    int c = lane & 15, q = lane >> 4, koff = q * 8;
    const u16 *Ab, *WT, *hWT; const float *bias, *hB; float* outp; int lda, K, m0;
    if (s < 256) { Ab = A.Zb2n; lda = 384; K = 384; WT = A.nW1T; bias = A.nb1s;
                   hWT = A.fnWT; hB = A.fnb; outp = A.outn; m0 = s * 16; }
    else { int t = s - 256; Ab = A.Zb2e; lda = 640; K = 640; WT = A.eW2T; bias = A.eb1;
           hWT = A.feWT; hB = A.feb; outp = A.oute; m0 = t * 16; }
    u16* L = lds[wv];
    const u16* Ap = Ab + (size_t)(m0 + c) * lda + koff;
    for (int half = 0; half < 2; ++half) {
        f32x4 acc[4] = {};
        const u16* Wp = WT + (size_t)(half * 64 + c) * K + koff;
        size_t ws = (size_t)16 * K;
        for (int k0 = 0; k0 < K; k0 += 32) {
            bf16x8 af = *(const bf16x8*)(Ap + k0);
#pragma unroll
            for (int nt = 0; nt < 4; ++nt) {
                bf16x8 bf = *(const bf16x8*)(Wp + nt * ws + k0);
                acc[nt] = __builtin_amdgcn_mfma_f32_16x16x32_bf16(af, bf, acc[nt], 0, 0, 0);
            }
        }
#pragma unroll
        for (int nt = 0; nt < 4; ++nt) {
            int col = half * 64 + nt * 16 + c;
            float bv = bias[col];
#pragma unroll
            for (int r = 0; r < 4; ++r)
                L[(q * 4 + r) * 128 + col] = f2bf(fmaxf(acc[nt][r] + bv, 0.f));
        }
    }
    f32x4 hacc[4] = {};
    const u16* Hp = hWT + (size_t)c * 128 + koff;
#pragma unroll
    for (int k0 = 0; k0 < 128; k0 += 32) {
        bf16x8 af = *(const bf16x8*)(L + c * 128 + koff + k0);
#pragma unroll
        for (int nt = 0; nt < 4; ++nt) {
            bf16x8 bf = *(const bf16x8*)(Hp + nt * 16 * 128 + k0);
            hacc[nt] = __builtin_amdgcn_mfma_f32_16x16x32_bf16(af, bf, hacc[nt], 0, 0, 0);
        }
    }
#pragma unroll
    for (int nt = 0; nt < 4; ++nt) {
        int col = nt * 16 + c;
        float bv = hB[col];
#pragma unroll
        for (int r = 0; r < 4; ++r)
            outp[(size_t)(m0 + q * 4 + r) * 64 + col] = hacc[nt][r] + bv;
    }
}

// ================= launch =================
extern "C" void kernel_launch(void* const* d_in, const int* in_sizes, int n_in,
                              void* d_out, int out_size, void* d_ws, size_t ws_size,
                              hipStream_t stream)
{
    const float* x    = (const float*)d_in[0];
    const float* ex   = (const float*)d_in[1];
    const int*   nei  = (const int*)d_in[2];
    const int*   eil  = (const int*)d_in[3];
    const float* eal  = (const float*)d_in[4];
    const int*   eiu  = (const int*)d_in[5];
    const float* eau  = (const float*)d_in[6];
    const float* nW0  = (const float*)d_in[7];
    const float* nb0  = (const float*)d_in[8];
    const float* nW1  = (const float*)d_in[9];
    const float* nb1  = (const float*)d_in[10];
    const float* fnW  = (const float*)d_in[11];
    const float* fnb  = (const float*)d_in[12];
    const float* eWl0 = (const float*)d_in[13];
    const float* eWu0 = (const float*)d_in[14];
    const float* eb0  = (const float*)d_in[15];
    const float* eWl1 = (const float*)d_in[16];
    const float* eWu1 = (const float*)d_in[17];
    const float* eb1  = (const float*)d_in[18];
    const float* feW  = (const float*)d_in[19];
    const float* feb  = (const float*)d_in[20];

    char* wsb = (char*)d_ws;
    size_t off = 0;
    auto alloc = [&](size_t bytes) { void* p = wsb + off; off += (bytes + 255) & ~(size_t)255; return p; };

    // ---- zeroed region (single small memset): all counters ----
    u32* cntA = (u32*)alloc(NN * 4);
    u32* cntL = (u32*)alloc(NE * 4);
    u32* cntU = (u32*)alloc(NE * 4);
    u32* cnt1A = (u32*)alloc(NN * 4);
    u32* cnt1L = (u32*)alloc(NE * 4);
    u32* cnt1U = (u32*)alloc(NE * 4);
    u32* cnt2A = (u32*)alloc(NN * 4);
    u32* cnt2L = (u32*)alloc(NE * 4);
    u32* cnt2U = (u32*)alloc(NE * 4);
    size_t zbytes = off;   // ~246 KB

    uint2* rb1A = (uint2*)alloc((size_t)NN * CAP * 8);
    uint2* rb1L = (uint2*)alloc((size_t)NE * CAP * 8);
    uint2* rb1U = (uint2*)alloc((size_t)NE * CAP * 8);
    uint2* rb2A = (uint2*)alloc((size_t)NN * CAP2 * 8);
    uint2* rb2L = (uint2*)alloc((size_t)NE * CAP2 * 8);
    uint2* rb2U = (uint2*)alloc((size_t)NE * CAP2 * 8);

    u32* colA = (u32*)alloc((size_t)NN * CAP * 4);
    u32* colL = (u32*)alloc((size_t)NE * CAP * 4);
    u32* colU = (u32*)alloc((size_t)NE * CAP * 4);
    u32* eidL = (u32*)alloc((size_t)NE * CAP * 4);
    u32* eidU = (u32*)alloc((size_t)NE * CAP * 4);

    u16* Zb1n = (u16*)alloc((size_t)4096 * 192 * 2);
    u16* Zb1e = (u16*)alloc((size_t)8192 * 160 * 2);
    u16* Zb2n = (u16*)alloc((size_t)4096 * 384 * 2);
    u16* Zb2e = (u16*)alloc((size_t)8192 * 640 * 2);

    u16* nW0T = (u16*)alloc((size_t)128 * 192 * 2);
    u16* nW1T = (u16*)alloc((size_t)128 * 384 * 2);
    u16* eW1T = (u16*)alloc((size_t)128 * 160 * 2);
    u16* eW2T = (u16*)alloc((size_t)128 * 640 * 2);
    u16* fnWT = (u16*)alloc((size_t)64 * 128 * 2);
    u16* feWT = (u16*)alloc((size_t)64 * 128 * 2);
    float* nb0s = (float*)alloc(128 * 4);
    float* nb1s = (float*)alloc(128 * 4);

    // ---- D0: zero counters (~246 KB) ----
    hipMemsetAsync(d_ws, 0, zbytes, stream);

    // ---- D1: prep + append ----
    PAArgs PA{x, ex, nW0, nW1, eWl0, eWu0, eWl1, eWu1, fnW, feW, nb0, nb1,
              nei, eil, eiu,
              cntA, cntL, cntU, colA, colL, colU, eidL, eidU,
              Zb1n, Zb1e, nW0T, nW1T, eW1T, eW2T, fnWT, feWT, nb0s, nb1s};
    prep_append<<<dim3(1024), dim3(256), 0, stream>>>(PA);

    // ---- D2: merged parallel resolve + square ----
    RQArgs RQ{cntA, cntL, cntU, colA, colL, colU, eidL, eidU, eal, eau,
              cnt1A, cnt1L, cnt1U, cnt2A, cnt2L, cnt2U,
              rb1A, rb1L, rb1U, rb2A, rb2L, rb2U};
    {
        int n = (NN + 2 * NE) * CAP;
        resolve_square_par<<<dim3((n + 255) / 256), dim3(256), 0, stream>>>(RQ);
    }

    // ---- D3: layer-1 spmm, both hops, 6 segments (width 4) ----
    {
        Seg6 P;
        P.s[0] = RSeg{cnt1A, rb1A, CAP,  Zb1n, Zb1n + 64,  NN << 4, 4, 192};
        P.s[1] = RSeg{cnt2A, rb2A, CAP2, Zb1n, Zb1n + 128, NN << 4, 4, 192};
        P.s[2] = RSeg{cnt1L, rb1L, CAP,  Zb1e, Zb1e + 32,  NE << 3, 3, 160};
        P.s[3] = RSeg{cnt2L, rb2L, CAP2, Zb1e, Zb1e + 64,  NE << 3, 3, 160};
        P.s[4] = RSeg{cnt1U, rb1U, CAP,  Zb1e, Zb1e + 96,  NE << 3, 3, 160};
        P.s[5] = RSeg{cnt2U, rb2U, CAP2, Zb1e, Zb1e + 128, NE << 3, 3, 160};
        int n = 2 * (NN << 4) + 4 * (NE << 3);
        spmm4_kernel<<<dim3((n + 255) / 256), dim3(256), 0, stream>>>(P);
    }

    // ---- D4: layer-1 GEMMs ----
    {
        G g0{Zb1n, 192, nW0T, 192, nb0s, Zb2n, 384};
        G g1{Zb1e, 160, eW1T, 160, eb0,  Zb2e, 640};
        gemm1_kernel<<<dim3(192, 2), dim3(256), 0, stream>>>(g0, g1);
    }

    // ---- D5: layer-2 spmm, both hops, 6 segments (width 8) ----
    {
        Seg6 P;
        P.s[0] = RSeg{cnt1A, rb1A, CAP,  Zb2n, Zb2n + 128, NN << 4, 4, 384};
        P.s[1] = RSeg{cnt2A, rb2A, CAP2, Zb2n, Zb2n + 256, NN << 4, 4, 384};
        P.s[2] = RSeg{cnt1L, rb1L, CAP,  Zb2e, Zb2e + 128, NE << 4, 4, 640};
        P.s[3] = RSeg{cnt2L, rb2L, CAP2, Zb2e, Zb2e + 256, NE << 4, 4, 640};
        P.s[4] = RSeg{cnt1U, rb1U, CAP,  Zb2e, Zb2e + 384, NE << 4, 4, 640};
        P.s[5] = RSeg{cnt2U, rb2U, CAP2, Zb2e, Zb2e + 512, NE << 4, 4, 640};
        int n = 2 * (NN << 4) + 4 * (NE << 4);
        spmm8_kernel<<<dim3((n + 255) / 256), dim3(256), 0, stream>>>(P);
    }

    // ---- D6: fused layer-2 GEMM + head ----
    GHArgs GH{Zb2n, Zb2e, nW1T, eW2T, fnWT, feWT,
              nb1s, eb1, fnb, feb,
              (float*)d_out, (float*)d_out + 262144};
    gemm2_head<<<dim3(192), dim3(256), 0, stream>>>(GH);
}

// Round 11
// 190.671 us; speedup vs baseline: 1.2705x; 1.2705x over previous
//
#include <hip/hip_runtime.h>

#define NN 4096
#define NE 8192
#define NLG 32768
#define CAP 32
#define CAP2 160   // 2-hop expansion bucket

typedef unsigned int u32;
typedef unsigned short u16;
typedef __attribute__((ext_vector_type(4))) float f32x4;
typedef __attribute__((ext_vector_type(8))) short bf16x8;
typedef __attribute__((ext_vector_type(8))) unsigned short u16x8;
typedef __attribute__((ext_vector_type(4))) unsigned short u16x4;

__device__ __forceinline__ float bf2f(u16 u) { return __uint_as_float(((u32)u) << 16); }
__device__ __forceinline__ u16 f2bf(float f) {
    u32 x = __float_as_uint(f);
    return (u16)((x + 0x7fffu + ((x >> 16) & 1u)) >> 16);  // RNE
}

// ================= K1: prep (converts/transposes/bias) + bucket append, fused =================
struct PAArgs {
    const float *x, *ex;
    const float *nW0, *nW1, *eWl0, *eWu0, *eWl1, *eWu1, *fnW, *feW, *nb0, *nb1;
    const int *nei, *eil, *eiu;
    u32 *cntA, *cntL, *cntU;            // raw counters (zeroed by memset)
    u32 *colA, *colL, *colU, *eidL, *eidU;
    u16 *Zb1n, *Zb1e, *nW0T, *nW1T, *eW1T, *eW2T, *fnWT, *feWT;
    float *nb0s, *nb1s;
};

__device__ __forceinline__ void wtrK(const float* src, u16* dst, u32 i, int Kp, int Nw, int ld, int kofs) {
    int nn = i / Kp, kk = i - nn * Kp;
    dst[(size_t)nn * ld + kofs + kk] = f2bf(src[(size_t)kk * Nw + nn]);
}
__device__ __forceinline__ void wtrS(const float* sa, const float* sb, u16* dst, u32 i, int Kp, int Nw, int ld) {
    int nn = i / Kp, kk = i - nn * Kp;
    dst[(size_t)nn * ld + kk] = f2bf(sa[(size_t)kk * Nw + nn] + sb[(size_t)kk * Nw + nn]);
}

__global__ __launch_bounds__(256) void prep_append(PAArgs A) {
    const u32 gid = blockIdx.x * blockDim.x + threadIdx.x;
    const u32 gsz = gridDim.x * blockDim.x;
    const u32 C0 = 65536;                 // x conv (f32x4 units)
    const u32 C1 = C0 + 65536;            // ex conv
    const u32 C2 = C1 + 24576;            // nW0T (Kp=192)
    const u32 C3 = C2 + 49152;            // nW1T (Kp=384)
    const u32 C4 = C3 + 4096;             // eW1T sum block (Kp=32)
    const u32 C5 = C4 + 4096;             // eWl0 k=1
    const u32 C6 = C5 + 4096;             // eWl0 k=2
    const u32 C7 = C6 + 4096;             // eWu0 k=1
    const u32 C8 = C7 + 4096;             // eWu0 k=2
    const u32 C9 = C8 + 16384;            // eW2T sum block (Kp=128)
    const u32 C10 = C9 + 16384;           // eWl1 k=1
    const u32 C11 = C10 + 16384;          // eWl1 k=2
    const u32 C12 = C11 + 16384;          // eWu1 k=1
    const u32 C13 = C12 + 16384;          // eWu1 k=2
    const u32 C14 = C13 + 8192;           // fnWT
    const u32 C15 = C14 + 8192;           // feWT
    const u32 C16 = C15 + 256;            // bias sums
    const u32 C17 = C16 + (NE + 2 * NLG); // append
    for (u32 i = gid; i < C17; i += gsz) {
        if (i < C0) {
            u32 t = i; int r = t >> 4, c4 = t & 15;
            f32x4 v = *(const f32x4*)(A.x + (size_t)t * 4);
            u16x4 o;
#pragma unroll
            for (int e = 0; e < 4; ++e) o[e] = f2bf(v[e]);
            *(u16x4*)(A.Zb1n + (size_t)r * 192 + c4 * 4) = o;
        } else if (i < C1) {
            u32 t = i - C0; int r = t >> 3, c4 = t & 7;
            f32x4 v = *(const f32x4*)(A.ex + (size_t)t * 4);
            u16x4 o;
#pragma unroll
            for (int e = 0; e < 4; ++e) o[e] = f2bf(v[e]);
            *(u16x4*)(A.Zb1e + (size_t)r * 160 + c4 * 4) = o;
        }
        else if (i < C2)  wtrK(A.nW0, A.nW0T, i - C1, 192, 128, 192, 0);
        else if (i < C3)  wtrK(A.nW1, A.nW1T, i - C2, 384, 128, 384, 0);
        else if (i < C4)  wtrS(A.eWl0, A.eWu0, A.eW1T, i - C3, 32, 128, 160);
        else if (i < C5)  wtrK(A.eWl0 + 32 * 128,     A.eW1T, i - C4, 32, 128, 160, 32);
        else if (i < C6)  wtrK(A.eWl0 + 2 * 32 * 128, A.eW1T, i - C5, 32, 128, 160, 64);
        else if (i < C7)  wtrK(A.eWu0 + 32 * 128,     A.eW1T, i - C6, 32, 128, 160, 96);
        else if (i < C8)  wtrK(A.eWu0 + 2 * 32 * 128, A.eW1T, i - C7, 32, 128, 160, 128);
        else if (i < C9)  wtrS(A.eWl1, A.eWu1, A.eW2T, i - C8, 128, 128, 640);
        else if (i < C10) wtrK(A.eWl1 + 128 * 128,     A.eW2T, i - C9, 128, 128, 640, 128);
        else if (i < C11) wtrK(A.eWl1 + 2 * 128 * 128, A.eW2T, i - C10, 128, 128, 640, 256);
        else if (i < C12) wtrK(A.eWu1 + 128 * 128,     A.eW2T, i - C11, 128, 128, 640, 384);
        else if (i < C13) wtrK(A.eWu1 + 2 * 128 * 128, A.eW2T, i - C12, 128, 128, 640, 512);
        else if (i < C14) wtrK(A.fnW, A.fnWT, i - C13, 128, 64, 128, 0);
        else if (i < C15) wtrK(A.feW, A.feWT, i - C14, 128, 64, 128, 0);
        else if (i < C16) {
            u32 t = i - C15;
            if (t < 128) { float s = 0.f; for (int k = 0; k < 3; ++k) s += A.nb0[k * 128 + t]; A.nb0s[t] = s; }
            else { t -= 128; float s = 0.f; for (int k = 0; k < 3; ++k) s += A.nb1[k * 128 + t]; A.nb1s[t] = s; }
        } else {
            u32 t = i - C16;
            if (t < NE) {
                int r = A.nei[t];
                u32 p = atomicAdd(&A.cntA[r], 1u);
                if (p < CAP) A.colA[r * CAP + p] = (u32)A.nei[NE + t];
            } else if (t < NE + NLG) {
                u32 e = t - NE;
                int r = A.eil[e];
                u32 p = atomicAdd(&A.cntL[r], 1u);
                if (p < CAP) { A.colL[r * CAP + p] = (u32)A.eil[NLG + e]; A.eidL[r * CAP + p] = e; }
            } else {
                u32 e = t - NE - NLG;
                int r = A.eiu[e];
                u32 p = atomicAdd(&A.cntU[r], 1u);
                if (p < CAP) { A.colU[r * CAP + p] = (u32)A.eiu[NLG + e]; A.eidU[r * CAP + p] = e; }
            }
        }
    }
}

// ================= K2: parallel resolve — one thread per (row, slot) =================
// A: first-index-wins (binary, value-identical). L/U: max-eid-wins (jnp last-set-wins).
struct RPArgs {
    const u32 *cntA, *cntL, *cntU;
    const u32 *colA, *colL, *colU, *eidL, *eidU;
    const float *eal, *eau;
    u32 *cnt1A, *cnt1L, *cnt1U;       // zeroed
    uint2 *rb1A, *rb1L, *rb1U;
};

__global__ __launch_bounds__(256) void resolve_par(RPArgs A) {
    u32 id = blockIdx.x * blockDim.x + threadIdx.x;
    const u32 NA = NN * CAP, NL = NE * CAP;
    if (id < NA) {
        u32 row = id >> 5, j = id & 31;
        u32 jn = A.cntA[row]; if (jn > CAP) jn = CAP;
        if (j >= jn) return;
        const u32* cp = A.colA + row * CAP;
        u32 cj = cp[j];
        for (u32 j2 = 0; j2 < j; ++j2) if (cp[j2] == cj) return;
        u32 pos = atomicAdd(&A.cnt1A[row], 1u);
        A.rb1A[row * CAP + pos] = make_uint2(cj, __float_as_uint(1.0f));
    } else if (id < NA + 2 * NL) {
        bool isL = id < NA + NL;
        u32 t = isL ? (id - NA) : (id - NA - NL);
        u32 row = t >> 5, j = t & 31;
        const u32* cnt = isL ? A.cntL : A.cntU;
        u32 jn = cnt[row]; if (jn > CAP) jn = CAP;
        if (j >= jn) return;
        const u32* cp = (isL ? A.colL : A.colU) + row * CAP;
        const u32* ep = (isL ? A.eidL : A.eidU) + row * CAP;
        u32 cj = cp[j], ej = ep[j];
        for (u32 j2 = 0; j2 < jn; ++j2)
            if (j2 != j && cp[j2] == cj && ep[j2] > ej) return;
        float w = (isL ? A.eal : A.eau)[ej];
        u32* c1 = isL ? A.cnt1L : A.cnt1U;
        uint2* rb = isL ? A.rb1L : A.rb1U;
        u32 pos = atomicAdd(&c1[row], 1u);
        rb[row * CAP + pos] = make_uint2(cj, __float_as_uint(w));
    }
}

// ================= K3: parallel square — expand deduped neighbor rows (reads rb1) =================
struct SQArgs {
    const u32 *cnt1A, *cnt1L, *cnt1U;
    const uint2 *rb1A, *rb1L, *rb1U;
    u32 *cnt2A, *cnt2L, *cnt2U;       // zeroed
    uint2 *rb2A, *rb2L, *rb2U;
};

__device__ __forceinline__ void square_one(const u32* cnt1, const uint2* rb1,
                                           u32* cnt2, uint2* rb2, u32 row, u32 j) {
    u32 jn = cnt1[row];
    if (j >= jn) return;
    uint2 q = rb1[row * CAP + j];
    float w1 = __uint_as_float(q.y);
    u32 cj = q.x;
    u32 kn = cnt1[cj];
    u32 off = atomicAdd(&cnt2[row], kn);
    const uint2* np = rb1 + cj * CAP;
    uint2* op = rb2 + (size_t)row * CAP2;
    for (u32 k = 0; k < kn; ++k) {
        u32 p = off + k;
        if (p < CAP2) {
            uint2 r = np[k];
            op[p] = make_uint2(r.x, __float_as_uint(w1 * __uint_as_float(r.y)));
        }
    }
}

__global__ __launch_bounds__(256) void square_par(SQArgs A) {
    u32 id = blockIdx.x * blockDim.x + threadIdx.x;
    const u32 NA = NN * CAP, NL = NE * CAP;
    if (id < NA) square_one(A.cnt1A, A.rb1A, A.cnt2A, A.rb2A, id >> 5, id & 31);
    else if (id < NA + NL) { u32 t = id - NA; square_one(A.cnt1L, A.rb1L, A.cnt2L, A.rb2L, t >> 5, t & 31); }
    else if (id < NA + 2 * NL) { u32 t = id - NA - NL; square_one(A.cnt1U, A.rb1U, A.cnt2U, A.rb2U, t >> 5, t & 31); }
}

// ================= one-hop gather SpMM over resolved buckets (exact counts), 6 segments =================
struct RSeg { const u32* cnt; const uint2* rb; u32 rbs; const u16* src; u16* dst; int n; int shift; int ld; };
struct Seg6 { RSeg s[6]; };

__device__ __forceinline__ void spmm_row8(const RSeg& s, int t) {
    int row = t >> s.shift, g = t & ((1 << s.shift) - 1);
    u32 jn = s.cnt[row]; if (jn > s.rbs) jn = s.rbs;
    const uint2* bp = s.rb + (size_t)row * s.rbs;
    const u16* srcg = s.src + g * 8;
    float acc[8] = {};
    u32 j = 0;
    for (; j + 4 <= jn; j += 4) {
        uint2 q0 = bp[j], q1 = bp[j + 1], q2 = bp[j + 2], q3 = bp[j + 3];
        u16x8 x0 = *(const u16x8*)(srcg + (size_t)q0.x * s.ld);
        u16x8 x1 = *(const u16x8*)(srcg + (size_t)q1.x * s.ld);
        u16x8 x2 = *(const u16x8*)(srcg + (size_t)q2.x * s.ld);
        u16x8 x3 = *(const u16x8*)(srcg + (size_t)q3.x * s.ld);
        float w0 = __uint_as_float(q0.y), w1 = __uint_as_float(q1.y);
        float w2 = __uint_as_float(q2.y), w3 = __uint_as_float(q3.y);
#pragma unroll
        for (int e = 0; e < 8; ++e) {
            acc[e] = fmaf(w0, bf2f(x0[e]), acc[e]);
            acc[e] = fmaf(w1, bf2f(x1[e]), acc[e]);
            acc[e] = fmaf(w2, bf2f(x2[e]), acc[e]);
            acc[e] = fmaf(w3, bf2f(x3[e]), acc[e]);
        }
    }
    for (; j < jn; ++j) {
        uint2 q = bp[j];
        u16x8 xv = *(const u16x8*)(srcg + (size_t)q.x * s.ld);
        float w = __uint_as_float(q.y);
#pragma unroll
        for (int e = 0; e < 8; ++e) acc[e] = fmaf(w, bf2f(xv[e]), acc[e]);
    }
    u16x8 o;
#pragma unroll
    for (int e = 0; e < 8; ++e) o[e] = f2bf(acc[e]);
    *(u16x8*)(s.dst + (size_t)row * s.ld + g * 8) = o;
}

__device__ __forceinline__ void spmm_row4(const RSeg& s, int t) {
    int row = t >> s.shift, g = t & ((1 << s.shift) - 1);
    u32 jn = s.cnt[row]; if (jn > s.rbs) jn = s.rbs;
    const uint2* bp = s.rb + (size_t)row * s.rbs;
    const u16* srcg = s.src + g * 4;
    float acc[4] = {};
    u32 j = 0;
    for (; j + 4 <= jn; j += 4) {
        uint2 q0 = bp[j], q1 = bp[j + 1], q2 = bp[j + 2], q3 = bp[j + 3];
        u16x4 x0 = *(const u16x4*)(srcg + (size_t)q0.x * s.ld);
        u16x4 x1 = *(const u16x4*)(srcg + (size_t)q1.x * s.ld);
        u16x4 x2 = *(const u16x4*)(srcg + (size_t)q2.x * s.ld);
        u16x4 x3 = *(const u16x4*)(srcg + (size_t)q3.x * s.ld);
        float w0 = __uint_as_float(q0.y), w1 = __uint_as_float(q1.y);
        float w2 = __uint_as_float(q2.y), w3 = __uint_as_float(q3.y);
#pragma unroll
        for (int e = 0; e < 4; ++e) {
            acc[e] = fmaf(w0, bf2f(x0[e]), acc[e]);
            acc[e] = fmaf(w1, bf2f(x1[e]), acc[e]);
            acc[e] = fmaf(w2, bf2f(x2[e]), acc[e]);
            acc[e] = fmaf(w3, bf2f(x3[e]), acc[e]);
        }
    }
    for (; j < jn; ++j) {
        uint2 q = bp[j];
        u16x4 xv = *(const u16x4*)(srcg + (size_t)q.x * s.ld);
        float w = __uint_as_float(q.y);
#pragma unroll
        for (int e = 0; e < 4; ++e) acc[e] = fmaf(w, bf2f(xv[e]), acc[e]);
    }
    u16x4 o;
#pragma unroll
    for (int e = 0; e < 4; ++e) o[e] = f2bf(acc[e]);
    *(u16x4*)(s.dst + (size_t)row * s.ld + g * 4) = o;
}

__global__ __launch_bounds__(256) void spmm4_kernel(Seg6 P) {
    int id = blockIdx.x * blockDim.x + threadIdx.x;
    int base = 0;
#pragma unroll
    for (int i = 0; i < 6; ++i) {
        int n = P.s[i].n;
        if (id < base + n) { spmm_row4(P.s[i], id - base); return; }
        base += n;
    }
}

__global__ __launch_bounds__(256) void spmm8_kernel(Seg6 P) {
    int id = blockIdx.x * blockDim.x + threadIdx.x;
    int base = 0;
#pragma unroll
    for (int i = 0; i < 6; ++i) {
        int n = P.s[i].n;
        if (id < base + n) { spmm_row8(P.s[i], id - base); return; }
        base += n;
    }
}

// ================= MFMA GEMM =================
struct G { const u16* Aa; int lda; const u16* WT; int K; const float* bias;
           u16* dst; int ldd; };

__device__ __forceinline__ void gemm_do(const G& g, int bx, int ny, int lane) {
    int m0 = bx * 16, n0 = ny * 64;
    int row = lane & 15, koff = (lane >> 4) * 8;
    f32x4 acc[4] = {};
    const u16* Ap = g.Aa + (size_t)(m0 + row) * g.lda + koff;
    const u16* Wp = g.WT + (size_t)(n0 + row) * g.K + koff;
    size_t ws = (size_t)16 * g.K;
    for (int k0 = 0; k0 < g.K; k0 += 32) {
        bf16x8 af = *(const bf16x8*)(Ap + k0);
#pragma unroll
        for (int nt = 0; nt < 4; ++nt) {
            bf16x8 bf = *(const bf16x8*)(Wp + nt * ws + k0);
            acc[nt] = __builtin_amdgcn_mfma_f32_16x16x32_bf16(af, bf, acc[nt], 0, 0, 0);
        }
    }
    int orow = m0 + (lane >> 4) * 4;
#pragma unroll
    for (int nt = 0; nt < 4; ++nt) {
        int col = n0 + nt * 16 + row;
        float bv = g.bias[col];
#pragma unroll
        for (int r = 0; r < 4; ++r) {
            float v = fmaxf(acc[nt][r] + bv, 0.f);  // relu
            g.dst[(size_t)(orow + r) * g.ldd + col] = f2bf(v);
        }
    }
}

__global__ __launch_bounds__(256) void gemm1_kernel(G g0, G g1) {
    int wv = threadIdx.x >> 6, lane = threadIdx.x & 63;
    int bxg = blockIdx.x * 4 + wv;
    int ny = blockIdx.y;
    if (bxg < 256) gemm_do(g0, bxg, ny, lane);
    else gemm_do(g1, bxg - 256, ny, lane);
}

// ================= fused layer-2 GEMM + output head =================
struct GHArgs {
    const u16 *Zb2n, *Zb2e, *nW1T, *eW2T, *fnWT, *feWT;
    const float *nb1s, *eb1, *fnb, *feb;
    float *outn, *oute;
};

__global__ __launch_bounds__(256) void gemm2_head(GHArgs A) {
    __shared__ u16 lds[4][16 * 128];
    int wv = threadIdx.x >> 6, lane = threadIdx.x & 63;
    int s = blockIdx.x * 4 + wv;
    int c = lane & 15, q = lane >> 4, koff = q * 8;
    const u16 *Ab, *WT, *hWT; const float *bias, *hB; float* outp; int lda, K, m0;
    if (s < 256) { Ab = A.Zb2n; lda = 384; K = 384; WT = A.nW1T; bias = A.nb1s;
                   hWT = A.fnWT; hB = A.fnb; outp = A.outn; m0 = s * 16; }
    else { int t = s - 256; Ab = A.Zb2e; lda = 640; K = 640; WT = A.eW2T; bias = A.eb1;
           hWT = A.feWT; hB = A.feb; outp = A.oute; m0 = t * 16; }
    u16* L = lds[wv];
    const u16* Ap = Ab + (size_t)(m0 + c) * lda + koff;
    for (int half = 0; half < 2; ++half) {
        f32x4 acc[4] = {};
        const u16* Wp = WT + (size_t)(half * 64 + c) * K + koff;
        size_t ws = (size_t)16 * K;
        for (int k0 = 0; k0 < K; k0 += 32) {
            bf16x8 af = *(const bf16x8*)(Ap + k0);
#pragma unroll
            for (int nt = 0; nt < 4; ++nt) {
                bf16x8 bf = *(const bf16x8*)(Wp + nt * ws + k0);
                acc[nt] = __builtin_amdgcn_mfma_f32_16x16x32_bf16(af, bf, acc[nt], 0, 0, 0);
            }
        }
#pragma unroll
        for (int nt = 0; nt < 4; ++nt) {
            int col = half * 64 + nt * 16 + c;
            float bv = bias[col];
#pragma unroll
            for (int r = 0; r < 4; ++r)
                L[(q * 4 + r) * 128 + col] = f2bf(fmaxf(acc[nt][r] + bv, 0.f));
        }
    }
    f32x4 hacc[4] = {};
    const u16* Hp = hWT + (size_t)c * 128 + koff;
#pragma unroll
    for (int k0 = 0; k0 < 128; k0 += 32) {
        bf16x8 af = *(const bf16x8*)(L + c * 128 + koff + k0);
#pragma unroll
        for (int nt = 0; nt < 4; ++nt) {
            bf16x8 bf = *(const bf16x8*)(Hp + nt * 16 * 128 + k0);
            hacc[nt] = __builtin_amdgcn_mfma_f32_16x16x32_bf16(af, bf, hacc[nt], 0, 0, 0);
        }
    }
#pragma unroll
    for (int nt = 0; nt < 4; ++nt) {
        int col = nt * 16 + c;
        float bv = hB[col];
#pragma unroll
        for (int r = 0; r < 4; ++r)
            outp[(size_t)(m0 + q * 4 + r) * 64 + col] = hacc[nt][r] + bv;
    }
}

// ================= launch =================
extern "C" void kernel_launch(void* const* d_in, const int* in_sizes, int n_in,
                              void* d_out, int out_size, void* d_ws, size_t ws_size,
                              hipStream_t stream)
{
    const float* x    = (const float*)d_in[0];
    const float* ex   = (const float*)d_in[1];
    const int*   nei  = (const int*)d_in[2];
    const int*   eil  = (const int*)d_in[3];
    const float* eal  = (const float*)d_in[4];
    const int*   eiu  = (const int*)d_in[5];
    const float* eau  = (const float*)d_in[6];
    const float* nW0  = (const float*)d_in[7];
    const float* nb0  = (const float*)d_in[8];
    const float* nW1  = (const float*)d_in[9];
    const float* nb1  = (const float*)d_in[10];
    const float* fnW  = (const float*)d_in[11];
    const float* fnb  = (const float*)d_in[12];
    const float* eWl0 = (const float*)d_in[13];
    const float* eWu0 = (const float*)d_in[14];
    const float* eb0  = (const float*)d_in[15];
    const float* eWl1 = (const float*)d_in[16];
    const float* eWu1 = (const float*)d_in[17];
    const float* eb1  = (const float*)d_in[18];
    const float* feW  = (const float*)d_in[19];
    const float* feb  = (const float*)d_in[20];

    char* wsb = (char*)d_ws;
    size_t off = 0;
    auto alloc = [&](size_t bytes) { void* p = wsb + off; off += (bytes + 255) & ~(size_t)255; return p; };

    // ---- zeroed region (single small memset): all counters ----
    u32* cntA = (u32*)alloc(NN * 4);
    u32* cntL = (u32*)alloc(NE * 4);
    u32* cntU = (u32*)alloc(NE * 4);
    u32* cnt1A = (u32*)alloc(NN * 4);
    u32* cnt1L = (u32*)alloc(NE * 4);
    u32* cnt1U = (u32*)alloc(NE * 4);
    u32* cnt2A = (u32*)alloc(NN * 4);
    u32* cnt2L = (u32*)alloc(NE * 4);
    u32* cnt2U = (u32*)alloc(NE * 4);
    size_t zbytes = off;   // ~246 KB

    uint2* rb1A = (uint2*)alloc((size_t)NN * CAP * 8);
    uint2* rb1L = (uint2*)alloc((size_t)NE * CAP * 8);
    uint2* rb1U = (uint2*)alloc((size_t)NE * CAP * 8);
    uint2* rb2A = (uint2*)alloc((size_t)NN * CAP2 * 8);
    uint2* rb2L = (uint2*)alloc((size_t)NE * CAP2 * 8);
    uint2* rb2U = (uint2*)alloc((size_t)NE * CAP2 * 8);

    u32* colA = (u32*)alloc((size_t)NN * CAP * 4);
    u32* colL = (u32*)alloc((size_t)NE * CAP * 4);
    u32* colU = (u32*)alloc((size_t)NE * CAP * 4);
    u32* eidL = (u32*)alloc((size_t)NE * CAP * 4);
    u32* eidU = (u32*)alloc((size_t)NE * CAP * 4);

    u16* Zb1n = (u16*)alloc((size_t)4096 * 192 * 2);
    u16* Zb1e = (u16*)alloc((size_t)8192 * 160 * 2);
    u16* Zb2n = (u16*)alloc((size_t)4096 * 384 * 2);
    u16* Zb2e = (u16*)alloc((size_t)8192 * 640 * 2);

    u16* nW0T = (u16*)alloc((size_t)128 * 192 * 2);
    u16* nW1T = (u16*)alloc((size_t)128 * 384 * 2);
    u16* eW1T = (u16*)alloc((size_t)128 * 160 * 2);
    u16* eW2T = (u16*)alloc((size_t)128 * 640 * 2);
    u16* fnWT = (u16*)alloc((size_t)64 * 128 * 2);
    u16* feWT = (u16*)alloc((size_t)64 * 128 * 2);
    float* nb0s = (float*)alloc(128 * 4);
    float* nb1s = (float*)alloc(128 * 4);

    // ---- D0: zero counters (~246 KB) ----
    hipMemsetAsync(d_ws, 0, zbytes, stream);

    // ---- D1: prep + append ----
    PAArgs PA{x, ex, nW0, nW1, eWl0, eWu0, eWl1, eWu1, fnW, feW, nb0, nb1,
              nei, eil, eiu,
              cntA, cntL, cntU, colA, colL, colU, eidL, eidU,
              Zb1n, Zb1e, nW0T, nW1T, eW1T, eW2T, fnWT, feWT, nb0s, nb1s};
    prep_append<<<dim3(1024), dim3(256), 0, stream>>>(PA);

    // ---- D2: parallel resolve ----
    RPArgs RP{cntA, cntL, cntU, colA, colL, colU, eidL, eidU, eal, eau,
              cnt1A, cnt1L, cnt1U, rb1A, rb1L, rb1U};
    {
        int n = (NN + 2 * NE) * CAP;
        resolve_par<<<dim3((n + 255) / 256), dim3(256), 0, stream>>>(RP);
    }

    // ---- D3: parallel square ----
    SQArgs SQ{cnt1A, cnt1L, cnt1U, rb1A, rb1L, rb1U,
              cnt2A, cnt2L, cnt2U, rb2A, rb2L, rb2U};
    {
        int n = (NN + 2 * NE) * CAP;
        square_par<<<dim3((n + 255) / 256), dim3(256), 0, stream>>>(SQ);
    }

    // ---- D4: layer-1 spmm, both hops, 6 segments (width 4) ----
    {
        Seg6 P;
        P.s[0] = RSeg{cnt1A, rb1A, CAP,  Zb1n, Zb1n + 64,  NN << 4, 4, 192};
        P.s[1] = RSeg{cnt2A, rb2A, CAP2, Zb1n, Zb1n + 128, NN << 4, 4, 192};
        P.s[2] = RSeg{cnt1L, rb1L, CAP,  Zb1e, Zb1e + 32,  NE << 3, 3, 160};
        P.s[3] = RSeg{cnt2L, rb2L, CAP2, Zb1e, Zb1e + 64,  NE << 3, 3, 160};
        P.s[4] = RSeg{cnt1U, rb1U, CAP,  Zb1e, Zb1e + 96,  NE << 3, 3, 160};
        P.s[5] = RSeg{cnt2U, rb2U, CAP2, Zb1e, Zb1e + 128, NE << 3, 3, 160};
        int n = 2 * (NN << 4) + 4 * (NE << 3);
        spmm4_kernel<<<dim3((n + 255) / 256), dim3(256), 0, stream>>>(P);
    }

    // ---- D5: layer-1 GEMMs ----
    {
        G g0{Zb1n, 192, nW0T, 192, nb0s, Zb2n, 384};
        G g1{Zb1e, 160, eW1T, 160, eb0,  Zb2e, 640};
        gemm1_kernel<<<dim3(192, 2), dim3(256), 0, stream>>>(g0, g1);
    }

    // ---- D6: layer-2 spmm, both hops, 6 segments (width 8) ----
    {
        Seg6 P;
        P.s[0] = RSeg{cnt1A, rb1A, CAP,  Zb2n, Zb2n + 128, NN << 4, 4, 384};
        P.s[1] = RSeg{cnt2A, rb2A, CAP2, Zb2n, Zb2n + 256, NN << 4, 4, 384};
        P.s[2] = RSeg{cnt1L, rb1L, CAP,  Zb2e, Zb2e + 128, NE << 4, 4, 640};
        P.s[3] = RSeg{cnt2L, rb2L, CAP2, Zb2e, Zb2e + 256, NE << 4, 4, 640};
        P.s[4] = RSeg{cnt1U, rb1U, CAP,  Zb2e, Zb2e + 384, NE << 4, 4, 640};
        P.s[5] = RSeg{cnt2U, rb2U, CAP2, Zb2e, Zb2e + 512, NE << 4, 4, 640};
        int n = 2 * (NN << 4) + 4 * (NE << 4);
        spmm8_kernel<<<dim3((n + 255) / 256), dim3(256), 0, stream>>>(P);
    }

    // ---- D7: fused layer-2 GEMM + head ----
    GHArgs GH{Zb2n, Zb2e, nW1T, eW2T, fnWT, feWT,
              nb1s, eb1, fnb, feb,
              (float*)d_out, (float*)d_out + 262144};
    gemm2_head<<<dim3(192), dim3(256), 0, stream>>>(GH);
}